// Round 7
// baseline (397.748 us; speedup 1.0000x reference)
//
#include <hip/hip_runtime.h>
#include <hip/hip_bf16.h>

#define NC 80
#define NK 51
#define REG_MAX 16
#define MAX_DET 100
#define A_TOT 8400
#define BS 16

// out layout (float32): num[16] | boxes[16*100*4] | scores[16*100] | classes[16*100] | kpts[16*100*17*3]
#define OUT_NUM 0
#define OUT_BOX 16
#define OUT_SCORE (16 + 16*MAX_DET*4)
#define OUT_CLASS (OUT_SCORE + 16*MAX_DET)
#define OUT_KPT (OUT_CLASS + 16*MAX_DET)

static __device__ __forceinline__ unsigned long long mk_key(unsigned u, int a) {
    return ((unsigned long long)u << 32) | (unsigned)(0x7FFFFFFF - a);
}

// -------- Kernel 1: fused class scores over all 3 levels --------
// 256 threads = 4 waves x 20 ocs; 256 anchors/block (4 per thread, float4).
// Features: LDS [32c][256a] staged per chunk. Weights: wave-uniform
// s_load_dwordx4 straight from global (scalar cache; 10KB/chunk working set
// shared by all waves) -> inner loop is 4 ds_read_b128 + 320 fmaf per step.
// __launch_bounds__(256,2): VGPR cap 256 so acc[20][4]+staging (~125) fits
// without spill (R6 spilled at default heuristic: VGPR_Count=76 < 80 accs).
__global__ __launch_bounds__(256, 2) void scores_fused(
    const float* __restrict__ x0, const float* __restrict__ x1, const float* __restrict__ x2,
    const float* __restrict__ w0, const float* __restrict__ w1, const float* __restrict__ w2,
    const float* __restrict__ bias0, const float* __restrict__ bias1, const float* __restrict__ bias2,
    float* __restrict__ max_s,       // [BS][A_TOT]
    int* __restrict__ cls_id)        // [BS][A_TOT]
{
    __shared__ float fs[32 * 256];   // 32 KB [c][a]; reused for argmax reduce

    int bid = blockIdx.x;
    const float *x, *w, *bias; int C, A, a_off, b, tile;
    if (bid < 32) {                  // level 2 first (longest serial work)
        x = x2; w = w2; bias = bias2; C = 512; A = 400; a_off = 8000;
        b = bid >> 1; tile = bid & 1;
    } else if (bid < 144) {          // level 1: 16 b x 7 tiles
        int r = bid - 32;
        x = x1; w = w1; bias = bias1; C = 256; A = 1600; a_off = 6400;
        b = r / 7; tile = r - b * 7;
    } else {                         // level 0: 16 b x 25 tiles
        int r = bid - 144;
        x = x0; w = w0; bias = bias0; C = 128; A = 6400; a_off = 0;
        b = r / 25; tile = r - b * 25;
    }
    int a0 = tile * 256;

    int t = threadIdx.x;
    int lane = t & 63;
    int lane4 = lane * 4;
    int wv = __builtin_amdgcn_readfirstlane(t >> 6);  // 0..3, wave-uniform
    int oc0 = wv * 20;
    const float* __restrict__ wbase = w + oc0 * C;    // wave-uniform base

    float acc[20][4];
#pragma unroll
    for (int j = 0; j < 20; ++j) {
        float bv = bias[oc0 + j];
#pragma unroll
        for (int an = 0; an < 4; ++an) acc[j][an] = bv;
    }

    const float* xb = x + (long)b * C * A;
    int nchunk = C >> 5;

    for (int kc = 0; kc < nchunk; ++kc) {
        __syncthreads();
        // stage features: 32 channels x 256 anchors (2048 float4, coalesced)
#pragma unroll
        for (int i = 0; i < 8; ++i) {
            int idx = t + i * 256;
            int c = idx >> 6;
            int q = (idx & 63) * 4;
            int aa = a0 + q; if (aa > A - 4) aa = A - 4;   // clamp; dups masked at write
            float4 v = *(const float4*)(xb + (long)(kc * 32 + c) * A + aa);
            *(float4*)(&fs[c * 256 + q]) = v;
        }
        __syncthreads();

        const float* __restrict__ wk = wbase + kc * 32;   // uniform
#pragma unroll 1
        for (int c4 = 0; c4 < 32; c4 += 4) {
            float4 f0 = *(const float4*)&fs[(c4 + 0) * 256 + lane4];
            float4 f1 = *(const float4*)&fs[(c4 + 1) * 256 + lane4];
            float4 f2 = *(const float4*)&fs[(c4 + 2) * 256 + lane4];
            float4 f3 = *(const float4*)&fs[(c4 + 3) * 256 + lane4];
#pragma unroll
            for (int j = 0; j < 20; ++j) {
                float4 wj = *(const float4*)(wk + j * C + c4);  // s_load_dwordx4
                acc[j][0] = fmaf(wj.x, f0.x, acc[j][0]);
                acc[j][0] = fmaf(wj.y, f1.x, acc[j][0]);
                acc[j][0] = fmaf(wj.z, f2.x, acc[j][0]);
                acc[j][0] = fmaf(wj.w, f3.x, acc[j][0]);
                acc[j][1] = fmaf(wj.x, f0.y, acc[j][1]);
                acc[j][1] = fmaf(wj.y, f1.y, acc[j][1]);
                acc[j][1] = fmaf(wj.z, f2.y, acc[j][1]);
                acc[j][1] = fmaf(wj.w, f3.y, acc[j][1]);
                acc[j][2] = fmaf(wj.x, f0.z, acc[j][2]);
                acc[j][2] = fmaf(wj.y, f1.z, acc[j][2]);
                acc[j][2] = fmaf(wj.z, f2.z, acc[j][2]);
                acc[j][2] = fmaf(wj.w, f3.z, acc[j][2]);
                acc[j][3] = fmaf(wj.x, f0.w, acc[j][3]);
                acc[j][3] = fmaf(wj.y, f1.w, acc[j][3]);
                acc[j][3] = fmaf(wj.z, f2.w, acc[j][3]);
                acc[j][3] = fmaf(wj.w, f3.w, acc[j][3]);
            }
        }
    }

    // per-thread argmax over 20 ocs for each of 4 anchors (first-max)
    float m[4]; int mi[4];
#pragma unroll
    for (int an = 0; an < 4; ++an) { m[an] = acc[0][an]; mi[an] = 0; }
#pragma unroll
    for (int j = 1; j < 20; ++j) {
#pragma unroll
        for (int an = 0; an < 4; ++an)
            if (acc[j][an] > m[an]) { m[an] = acc[j][an]; mi[an] = j; }
    }

    __syncthreads();
    float* rm = fs;                  // [4][256] reuse
    int*   ri = (int*)(fs + 1024);   // [4][256]
#pragma unroll
    for (int an = 0; an < 4; ++an) {
        rm[wv * 256 + lane4 + an] = m[an];
        ri[wv * 256 + lane4 + an] = mi[an] + oc0;
    }
    __syncthreads();

    if (t < 256) {
        float bm = rm[t]; int bi = ri[t];
#pragma unroll
        for (int v = 1; v < 4; ++v) {
            float om = rm[v * 256 + t];
            if (om > bm) { bm = om; bi = ri[v * 256 + t]; }  // ascending oc keeps first max
        }
        int ga = a0 + t;
        if (ga < A) {
            max_s[b * A_TOT + a_off + ga] = 1.0f / (1.0f + expf(-bm));
            cls_id[b * A_TOT + a_off + ga] = bi;
        }
    }
}

// -------- Kernel 2: exact top-100 per batch via radix select --------
__global__ __launch_bounds__(1024) void topk_kernel(
    const float* __restrict__ max_s, // [BS][A_TOT]
    const int* __restrict__ cls_id,  // [BS][A_TOT]
    float* __restrict__ out,
    int* __restrict__ top_idx)       // [BS][MAX_DET]
{
    int b = blockIdx.x;
    int t = threadIdx.x;
    int wv = t >> 6;

    __shared__ unsigned hist[16 * 256];
    __shared__ unsigned suffix[256];
    __shared__ int tieIdx[A_TOT];
    __shared__ unsigned long long highKeys[128];
    __shared__ unsigned long long finalKeys[128];
    __shared__ int wmin[16];
    __shared__ unsigned s_prefix;
    __shared__ int s_k, s_selD, s_nHigh, s_nTie, s_cnt, s_bcast;

    unsigned u[9];
    bool val[9];
#pragma unroll
    for (int i = 0; i < 9; ++i) {
        int a = t + i * 1024;
        val[i] = (a < A_TOT);
        u[i] = val[i] ? __float_as_uint(max_s[b * A_TOT + a]) : 0u;
    }

    if (t == 0) { s_prefix = 0; s_k = MAX_DET; s_nHigh = 0; s_nTie = 0; s_cnt = 0; }

    for (int pass = 0; pass < 4; ++pass) {
#pragma unroll
        for (int j = 0; j < 4; ++j) hist[t + j * 1024] = 0;
        if (t == 0) s_selD = 0;
        __syncthreads();

        unsigned pre = s_prefix;
        int k = s_k;
        int shHi = 32 - 8 * pass;
        int shD = 24 - 8 * pass;
#pragma unroll
        for (int i = 0; i < 9; ++i) {
            if (val[i]) {
                bool cand = (pass == 0) ? true : ((u[i] >> shHi) == pre);
                if (cand)
                    atomicAdd(&hist[(wv << 8) + ((u[i] >> shD) & 0xFF)], 1u);
            }
        }
        __syncthreads();

        if (t < 256) {
            unsigned s = 0;
#pragma unroll
            for (int w = 0; w < 16; ++w) s += hist[(w << 8) + t];
            suffix[t] = s;
        }
        __syncthreads();
        for (int off = 1; off < 256; off <<= 1) {
            unsigned v = 0;
            if (t < 256) v = suffix[t] + ((t + off < 256) ? suffix[t + off] : 0u);
            __syncthreads();
            if (t < 256) suffix[t] = v;
            __syncthreads();
        }
        if (t < 256 && suffix[t] >= (unsigned)k) atomicMax(&s_selD, t);
        __syncthreads();
        if (t == 0) {
            int d = s_selD;
            s_k = k - ((d < 255) ? (int)suffix[d + 1] : 0);
            s_prefix = (pre << 8) | (unsigned)d;
        }
        __syncthreads();
    }

    unsigned cut = s_prefix;
    int r = s_k;

#pragma unroll
    for (int i = 0; i < 9; ++i) {
        if (val[i]) {
            int a = t + i * 1024;
            if (u[i] > cut) {
                int p = atomicAdd(&s_nHigh, 1);
                highKeys[p] = mk_key(u[i], a);
            } else if (u[i] == cut) {
                int p = atomicAdd(&s_nTie, 1);
                tieIdx[p] = a;
            }
        }
    }
    __syncthreads();
    int m = s_nHigh;
    int nt = s_nTie;

    if (t < 128) finalKeys[t] = 0ull;
    __syncthreads();
    if (t < m) finalKeys[t] = highKeys[t];

    if (nt == r) {
        if (t < nt) finalKeys[m + t] = mk_key(cut, tieIdx[t]);
        __syncthreads();
    } else {
        __syncthreads();
        for (int j = 0; j < r; ++j) {
            int mn = 0x7FFFFFFF;
            for (int p = t; p < nt; p += 1024) mn = min(mn, tieIdx[p]);
            for (int off = 32; off > 0; off >>= 1) mn = min(mn, __shfl_down(mn, off, 64));
            if ((t & 63) == 0) wmin[wv] = mn;
            __syncthreads();
            if (t == 0) {
                int v = wmin[0];
#pragma unroll
                for (int w = 1; w < 16; ++w) v = min(v, wmin[w]);
                s_bcast = v;
                finalKeys[m + j] = mk_key(cut, v);
            }
            __syncthreads();
            int v = s_bcast;
            for (int p = t; p < nt; p += 1024)
                if (tieIdx[p] == v) tieIdx[p] = 0x7FFFFFFF;
            __syncthreads();
        }
    }

    for (int ksz = 2; ksz <= 128; ksz <<= 1) {
        for (int j = ksz >> 1; j > 0; j >>= 1) {
            if (t < 128) {
                int ixj = t ^ j;
                if (ixj > t) {
                    bool desc = ((t & ksz) == 0);
                    unsigned long long x = finalKeys[t], y = finalKeys[ixj];
                    bool sw = desc ? (x < y) : (x > y);
                    if (sw) { finalKeys[t] = y; finalKeys[ixj] = x; }
                }
            }
            __syncthreads();
        }
    }

    if (t < MAX_DET) {
        unsigned long long kk = finalKeys[t];
        float sc = __uint_as_float((unsigned)(kk >> 32));
        int a = 0x7FFFFFFF - (int)(kk & 0xFFFFFFFFull);
        out[OUT_SCORE + b * MAX_DET + t] = sc;
        out[OUT_CLASS + b * MAX_DET + t] = (float)cls_id[b * A_TOT + a];
        top_idx[b * MAX_DET + t] = a;
        if (sc > 0.25f) atomicAdd(&s_cnt, 1);
    }
    __syncthreads();
    if (t == 0) out[OUT_NUM + b] = (float)s_cnt;
}

// -------- Kernel 3: decode box + kpts for selected anchors only --------
__global__ __launch_bounds__(128) void decode_kernel(
    const float* __restrict__ x0, const float* __restrict__ x1, const float* __restrict__ x2,
    const float* __restrict__ w2_0, const float* __restrict__ b2_0,
    const float* __restrict__ w2_1, const float* __restrict__ b2_1,
    const float* __restrict__ w2_2, const float* __restrict__ b2_2,
    const float* __restrict__ w4_0, const float* __restrict__ b4_0,
    const float* __restrict__ w4_1, const float* __restrict__ b4_1,
    const float* __restrict__ w4_2, const float* __restrict__ b4_2,
    const int* __restrict__ top_idx,
    float* __restrict__ out)
{
    int b = blockIdx.y;
    int k = blockIdx.x;
    int a = top_idx[b * MAX_DET + k];

    const float* x; const float* w2; const float* bb2; const float* w4; const float* bb4;
    int C, A, W, a_local; float stride;
    if (a < 6400)      { x = x0; C = 128; A = 6400; W = 80; stride = 8.0f;  a_local = a;        w2 = w2_0; bb2 = b2_0; w4 = w4_0; bb4 = b4_0; }
    else if (a < 8000) { x = x1; C = 256; A = 1600; W = 40; stride = 16.0f; a_local = a - 6400; w2 = w2_1; bb2 = b2_1; w4 = w4_1; bb4 = b4_1; }
    else               { x = x2; C = 512; A = 400;  W = 20; stride = 32.0f; a_local = a - 8000; w2 = w2_2; bb2 = b2_2; w4 = w4_2; bb4 = b4_2; }

    __shared__ float fs[512];
    __shared__ float logits[64];
    __shared__ float kraw[NK];
    __shared__ float dist[4];

    int t = threadIdx.x;
    for (int c = t; c < C; c += 128)
        fs[c] = x[((long)b * C + c) * A + a_local];
    __syncthreads();

    if (t < 64 + NK) {
        const float* wrow; float acc;
        if (t < 64) { wrow = w2 + t * C; acc = bb2[t]; }
        else        { wrow = w4 + (t - 64) * C; acc = bb4[t - 64]; }
#pragma unroll 4
        for (int c = 0; c < C; c += 8) {
            float4 wa = *(const float4*)(wrow + c);
            float4 wb = *(const float4*)(wrow + c + 4);
            float4 fa = *(const float4*)&fs[c];
            float4 fb = *(const float4*)&fs[c + 4];
            acc = fmaf(wa.x, fa.x, acc);
            acc = fmaf(wa.y, fa.y, acc);
            acc = fmaf(wa.z, fa.z, acc);
            acc = fmaf(wa.w, fa.w, acc);
            acc = fmaf(wb.x, fb.x, acc);
            acc = fmaf(wb.y, fb.y, acc);
            acc = fmaf(wb.z, fb.z, acc);
            acc = fmaf(wb.w, fb.w, acc);
        }
        if (t < 64) logits[t] = acc;
        else        kraw[t - 64] = acc;
    }
    __syncthreads();

    if (t < 4) {
        float mx = logits[t * 16];
#pragma unroll
        for (int r = 1; r < 16; ++r) mx = fmaxf(mx, logits[t * 16 + r]);
        float se = 0.0f, sw = 0.0f;
#pragma unroll
        for (int r = 0; r < 16; ++r) {
            float e = expf(logits[t * 16 + r] - mx);
            se += e; sw += e * (float)r;
        }
        dist[t] = sw / se;
    }
    __syncthreads();

    float ax = (float)(a_local % W) + 0.5f;
    float ay = (float)(a_local / W) + 0.5f;

    if (t == 0) {
        float x1c = ax - dist[0], y1c = ay - dist[1];
        float x2c = ax + dist[2], y2c = ay + dist[3];
        float* ob = out + OUT_BOX + ((long)b * MAX_DET + k) * 4;
        ob[0] = (x1c + x2c) * 0.5f * stride;
        ob[1] = (y1c + y2c) * 0.5f * stride;
        ob[2] = (x2c - x1c) * stride;
        ob[3] = (y2c - y1c) * stride;
    }
    if (t < 17) {
        float vx = kraw[t * 3], vy = kraw[t * 3 + 1], vv = kraw[t * 3 + 2];
        float gx = ax - 0.5f, gy = ay - 0.5f;
        float* ok = out + OUT_KPT + (((long)b * MAX_DET + k) * 17 + t) * 3;
        ok[0] = (vx * 2.0f + gx) * stride;
        ok[1] = (vy * 2.0f + gy) * stride;
        ok[2] = 1.0f / (1.0f + expf(-vv));
    }
}

extern "C" void kernel_launch(void* const* d_in, const int* in_sizes, int n_in,
                              void* d_out, int out_size, void* d_ws, size_t ws_size,
                              hipStream_t stream) {
    const float* x0 = (const float*)d_in[0];
    const float* x1 = (const float*)d_in[1];
    const float* x2 = (const float*)d_in[2];
    const float* w2[3] = {(const float*)d_in[3], (const float*)d_in[5], (const float*)d_in[7]};
    const float* b2[3] = {(const float*)d_in[4], (const float*)d_in[6], (const float*)d_in[8]};
    const float* w3[3] = {(const float*)d_in[9], (const float*)d_in[11], (const float*)d_in[13]};
    const float* b3[3] = {(const float*)d_in[10], (const float*)d_in[12], (const float*)d_in[14]};
    const float* w4[3] = {(const float*)d_in[15], (const float*)d_in[17], (const float*)d_in[19]};
    const float* b4[3] = {(const float*)d_in[16], (const float*)d_in[18], (const float*)d_in[20]};

    float* out = (float*)d_out;

    float* ws_maxs = (float*)d_ws;                    // [16][8400]
    int* ws_cls = (int*)(ws_maxs + BS * A_TOT);       // [16][8400]
    int* ws_top = (int*)(ws_cls + BS * A_TOT);        // [16][100]

    // fused scores: 32 (L2) + 112 (L1) + 400 (L0) blocks, 256 anchors each
    scores_fused<<<dim3(544), 256, 0, stream>>>(
        x0, x1, x2, w3[0], w3[1], w3[2], b3[0], b3[1], b3[2], ws_maxs, ws_cls);
    topk_kernel<<<dim3(BS), 1024, 0, stream>>>(ws_maxs, ws_cls, out, ws_top);
    decode_kernel<<<dim3(MAX_DET, BS), 128, 0, stream>>>(
        x0, x1, x2,
        w2[0], b2[0], w2[1], b2[1], w2[2], b2[2],
        w4[0], b4[0], w4[1], b4[1], w4[2], b4[2],
        ws_top, out);
}

// Round 8
// 313.664 us; speedup vs baseline: 1.2681x; 1.2681x over previous
//
#include <hip/hip_runtime.h>
#include <hip/hip_bf16.h>

#define NC 80
#define NK 51
#define REG_MAX 16
#define MAX_DET 100
#define A_TOT 8400
#define BS 16

// out layout (float32): num[16] | boxes[16*100*4] | scores[16*100] | classes[16*100] | kpts[16*100*17*3]
#define OUT_NUM 0
#define OUT_BOX 16
#define OUT_SCORE (16 + 16*MAX_DET*4)
#define OUT_CLASS (OUT_SCORE + 16*MAX_DET)
#define OUT_KPT (OUT_CLASS + 16*MAX_DET)

static __device__ __forceinline__ unsigned long long mk_key(unsigned u, int a) {
    return ((unsigned long long)u << 32) | (unsigned)(0x7FFFFFFF - a);
}

// -------- Kernel 1: fused class scores over all 3 levels --------
// 256 threads = 4 waves x 20 ocs; 256 anchors/block (4 per thread).
// Weights staged in LDS (broadcast ds_read_b128); features in LDS [c][a],
// read as b128 (4 anchors). Per 4-ch step: 24 LDS instr per 320 FMAs.
// __launch_bounds__(256,2): VGPR budget 256 so acc[20][4]+staging (~130)
// fits WITHOUT spill. (R6 = same code at default bounds -> allocator gave
// 76 VGPR < 80 accs -> spilled. R4 = 2 anchors, no spill, 103us, but 3.6x
// LDS-pipe oversubscribed; this halves LDS instr per FMA.)
__global__ __launch_bounds__(256, 2) void scores_fused(
    const float* __restrict__ x0, const float* __restrict__ x1, const float* __restrict__ x2,
    const float* __restrict__ w0, const float* __restrict__ w1, const float* __restrict__ w2,
    const float* __restrict__ bias0, const float* __restrict__ bias1, const float* __restrict__ bias2,
    float* __restrict__ max_s,       // [BS][A_TOT]
    int* __restrict__ cls_id)        // [BS][A_TOT]
{
    __shared__ float fs[32 * 256];   // 32 KB [c][a]; reused for argmax reduce
    __shared__ float wsh[80 * 32];   // 10 KB [oc][c]

    int bid = blockIdx.x;
    const float *x, *w, *bias; int C, A, a_off, b, tile;
    if (bid < 32) {                  // level 2 first (longest serial work)
        x = x2; w = w2; bias = bias2; C = 512; A = 400; a_off = 8000;
        b = bid >> 1; tile = bid & 1;
    } else if (bid < 144) {          // level 1: 16 b x 7 tiles
        int r = bid - 32;
        x = x1; w = w1; bias = bias1; C = 256; A = 1600; a_off = 6400;
        b = r / 7; tile = r - b * 7;
    } else {                         // level 0: 16 b x 25 tiles
        int r = bid - 144;
        x = x0; w = w0; bias = bias0; C = 128; A = 6400; a_off = 0;
        b = r / 25; tile = r - b * 25;
    }
    int a0 = tile * 256;

    int t = threadIdx.x;
    int lane = t & 63;
    int lane4 = lane * 4;
    int wv = __builtin_amdgcn_readfirstlane(t >> 6);  // 0..3, wave-uniform
    int oc0 = wv * 20;

    float acc[20][4];
#pragma unroll
    for (int j = 0; j < 20; ++j) {
        float bv = bias[oc0 + j];
#pragma unroll
        for (int an = 0; an < 4; ++an) acc[j][an] = bv;
    }

    const float* xb = x + (long)b * C * A;
    int nchunk = C >> 5;

    for (int kc = 0; kc < nchunk; ++kc) {
        __syncthreads();
        // stage features: 32 channels x 256 anchors (2048 float4)
#pragma unroll
        for (int i = 0; i < 8; ++i) {
            int idx = t + i * 256;
            int c = idx >> 6;
            int q = (idx & 63) * 4;
            int aa = a0 + q; if (aa > A - 4) aa = A - 4;   // clamp; dups masked at write
            float4 v = *(const float4*)(xb + (long)(kc * 32 + c) * A + aa);
            *(float4*)(&fs[c * 256 + q]) = v;
        }
        // stage weights: 80 ocs x 32 channels (640 float4)
#pragma unroll
        for (int i = 0; i < 3; ++i) {
            int idx = t + i * 256;
            if (idx < 640) {
                int oc = idx >> 3;
                int q = (idx & 7) * 4;
                float4 v = *(const float4*)(w + oc * C + kc * 32 + q);
                *(float4*)(&wsh[oc * 32 + q]) = v;
            }
        }
        __syncthreads();

#pragma unroll 1
        for (int c4 = 0; c4 < 32; c4 += 4) {
            float4 f0 = *(const float4*)&fs[(c4 + 0) * 256 + lane4];
            float4 f1 = *(const float4*)&fs[(c4 + 1) * 256 + lane4];
            float4 f2 = *(const float4*)&fs[(c4 + 2) * 256 + lane4];
            float4 f3 = *(const float4*)&fs[(c4 + 3) * 256 + lane4];
#pragma unroll
            for (int j = 0; j < 20; ++j) {
                float4 wj = *(const float4*)(&wsh[(oc0 + j) * 32 + c4]);  // broadcast
                acc[j][0] = fmaf(wj.x, f0.x, acc[j][0]);
                acc[j][0] = fmaf(wj.y, f1.x, acc[j][0]);
                acc[j][0] = fmaf(wj.z, f2.x, acc[j][0]);
                acc[j][0] = fmaf(wj.w, f3.x, acc[j][0]);
                acc[j][1] = fmaf(wj.x, f0.y, acc[j][1]);
                acc[j][1] = fmaf(wj.y, f1.y, acc[j][1]);
                acc[j][1] = fmaf(wj.z, f2.y, acc[j][1]);
                acc[j][1] = fmaf(wj.w, f3.y, acc[j][1]);
                acc[j][2] = fmaf(wj.x, f0.z, acc[j][2]);
                acc[j][2] = fmaf(wj.y, f1.z, acc[j][2]);
                acc[j][2] = fmaf(wj.z, f2.z, acc[j][2]);
                acc[j][2] = fmaf(wj.w, f3.z, acc[j][2]);
                acc[j][3] = fmaf(wj.x, f0.w, acc[j][3]);
                acc[j][3] = fmaf(wj.y, f1.w, acc[j][3]);
                acc[j][3] = fmaf(wj.z, f2.w, acc[j][3]);
                acc[j][3] = fmaf(wj.w, f3.w, acc[j][3]);
            }
        }
    }

    // per-thread argmax over 20 ocs for each of 4 anchors (first-max)
    float m[4]; int mi[4];
#pragma unroll
    for (int an = 0; an < 4; ++an) { m[an] = acc[0][an]; mi[an] = 0; }
#pragma unroll
    for (int j = 1; j < 20; ++j) {
#pragma unroll
        for (int an = 0; an < 4; ++an)
            if (acc[j][an] > m[an]) { m[an] = acc[j][an]; mi[an] = j; }
    }

    __syncthreads();
    float* rm = fs;                  // [4][256] reuse
    int*   ri = (int*)(fs + 1024);   // [4][256]
#pragma unroll
    for (int an = 0; an < 4; ++an) {
        rm[wv * 256 + lane4 + an] = m[an];
        ri[wv * 256 + lane4 + an] = mi[an] + oc0;
    }
    __syncthreads();

    if (t < 256) {
        float bm = rm[t]; int bi = ri[t];
#pragma unroll
        for (int v = 1; v < 4; ++v) {
            float om = rm[v * 256 + t];
            if (om > bm) { bm = om; bi = ri[v * 256 + t]; }  // ascending oc keeps first max
        }
        int ga = a0 + t;
        if (ga < A) {
            max_s[b * A_TOT + a_off + ga] = 1.0f / (1.0f + expf(-bm));
            cls_id[b * A_TOT + a_off + ga] = bi;
        }
    }
}

// -------- Kernel 2: exact top-100 per batch via radix select --------
__global__ __launch_bounds__(1024) void topk_kernel(
    const float* __restrict__ max_s, // [BS][A_TOT]
    const int* __restrict__ cls_id,  // [BS][A_TOT]
    float* __restrict__ out,
    int* __restrict__ top_idx)       // [BS][MAX_DET]
{
    int b = blockIdx.x;
    int t = threadIdx.x;
    int wv = t >> 6;

    __shared__ unsigned hist[16 * 256];
    __shared__ unsigned suffix[256];
    __shared__ int tieIdx[A_TOT];
    __shared__ unsigned long long highKeys[128];
    __shared__ unsigned long long finalKeys[128];
    __shared__ int wmin[16];
    __shared__ unsigned s_prefix;
    __shared__ int s_k, s_selD, s_nHigh, s_nTie, s_cnt, s_bcast;

    unsigned u[9];
    bool val[9];
#pragma unroll
    for (int i = 0; i < 9; ++i) {
        int a = t + i * 1024;
        val[i] = (a < A_TOT);
        u[i] = val[i] ? __float_as_uint(max_s[b * A_TOT + a]) : 0u;
    }

    if (t == 0) { s_prefix = 0; s_k = MAX_DET; s_nHigh = 0; s_nTie = 0; s_cnt = 0; }

    for (int pass = 0; pass < 4; ++pass) {
#pragma unroll
        for (int j = 0; j < 4; ++j) hist[t + j * 1024] = 0;
        if (t == 0) s_selD = 0;
        __syncthreads();

        unsigned pre = s_prefix;
        int k = s_k;
        int shHi = 32 - 8 * pass;
        int shD = 24 - 8 * pass;
#pragma unroll
        for (int i = 0; i < 9; ++i) {
            if (val[i]) {
                bool cand = (pass == 0) ? true : ((u[i] >> shHi) == pre);
                if (cand)
                    atomicAdd(&hist[(wv << 8) + ((u[i] >> shD) & 0xFF)], 1u);
            }
        }
        __syncthreads();

        if (t < 256) {
            unsigned s = 0;
#pragma unroll
            for (int w = 0; w < 16; ++w) s += hist[(w << 8) + t];
            suffix[t] = s;
        }
        __syncthreads();
        for (int off = 1; off < 256; off <<= 1) {
            unsigned v = 0;
            if (t < 256) v = suffix[t] + ((t + off < 256) ? suffix[t + off] : 0u);
            __syncthreads();
            if (t < 256) suffix[t] = v;
            __syncthreads();
        }
        if (t < 256 && suffix[t] >= (unsigned)k) atomicMax(&s_selD, t);
        __syncthreads();
        if (t == 0) {
            int d = s_selD;
            s_k = k - ((d < 255) ? (int)suffix[d + 1] : 0);
            s_prefix = (pre << 8) | (unsigned)d;
        }
        __syncthreads();
    }

    unsigned cut = s_prefix;
    int r = s_k;

#pragma unroll
    for (int i = 0; i < 9; ++i) {
        if (val[i]) {
            int a = t + i * 1024;
            if (u[i] > cut) {
                int p = atomicAdd(&s_nHigh, 1);
                highKeys[p] = mk_key(u[i], a);
            } else if (u[i] == cut) {
                int p = atomicAdd(&s_nTie, 1);
                tieIdx[p] = a;
            }
        }
    }
    __syncthreads();
    int m = s_nHigh;
    int nt = s_nTie;

    if (t < 128) finalKeys[t] = 0ull;
    __syncthreads();
    if (t < m) finalKeys[t] = highKeys[t];

    if (nt == r) {
        if (t < nt) finalKeys[m + t] = mk_key(cut, tieIdx[t]);
        __syncthreads();
    } else {
        __syncthreads();
        for (int j = 0; j < r; ++j) {
            int mn = 0x7FFFFFFF;
            for (int p = t; p < nt; p += 1024) mn = min(mn, tieIdx[p]);
            for (int off = 32; off > 0; off >>= 1) mn = min(mn, __shfl_down(mn, off, 64));
            if ((t & 63) == 0) wmin[wv] = mn;
            __syncthreads();
            if (t == 0) {
                int v = wmin[0];
#pragma unroll
                for (int w = 1; w < 16; ++w) v = min(v, wmin[w]);
                s_bcast = v;
                finalKeys[m + j] = mk_key(cut, v);
            }
            __syncthreads();
            int v = s_bcast;
            for (int p = t; p < nt; p += 1024)
                if (tieIdx[p] == v) tieIdx[p] = 0x7FFFFFFF;
            __syncthreads();
        }
    }

    for (int ksz = 2; ksz <= 128; ksz <<= 1) {
        for (int j = ksz >> 1; j > 0; j >>= 1) {
            if (t < 128) {
                int ixj = t ^ j;
                if (ixj > t) {
                    bool desc = ((t & ksz) == 0);
                    unsigned long long x = finalKeys[t], y = finalKeys[ixj];
                    bool sw = desc ? (x < y) : (x > y);
                    if (sw) { finalKeys[t] = y; finalKeys[ixj] = x; }
                }
            }
            __syncthreads();
        }
    }

    if (t < MAX_DET) {
        unsigned long long kk = finalKeys[t];
        float sc = __uint_as_float((unsigned)(kk >> 32));
        int a = 0x7FFFFFFF - (int)(kk & 0xFFFFFFFFull);
        out[OUT_SCORE + b * MAX_DET + t] = sc;
        out[OUT_CLASS + b * MAX_DET + t] = (float)cls_id[b * A_TOT + a];
        top_idx[b * MAX_DET + t] = a;
        if (sc > 0.25f) atomicAdd(&s_cnt, 1);
    }
    __syncthreads();
    if (t == 0) out[OUT_NUM + b] = (float)s_cnt;
}

// -------- Kernel 3: decode box + kpts for selected anchors only --------
__global__ __launch_bounds__(128) void decode_kernel(
    const float* __restrict__ x0, const float* __restrict__ x1, const float* __restrict__ x2,
    const float* __restrict__ w2_0, const float* __restrict__ b2_0,
    const float* __restrict__ w2_1, const float* __restrict__ b2_1,
    const float* __restrict__ w2_2, const float* __restrict__ b2_2,
    const float* __restrict__ w4_0, const float* __restrict__ b4_0,
    const float* __restrict__ w4_1, const float* __restrict__ b4_1,
    const float* __restrict__ w4_2, const float* __restrict__ b4_2,
    const int* __restrict__ top_idx,
    float* __restrict__ out)
{
    int b = blockIdx.y;
    int k = blockIdx.x;
    int a = top_idx[b * MAX_DET + k];

    const float* x; const float* w2; const float* bb2; const float* w4; const float* bb4;
    int C, A, W, a_local; float stride;
    if (a < 6400)      { x = x0; C = 128; A = 6400; W = 80; stride = 8.0f;  a_local = a;        w2 = w2_0; bb2 = b2_0; w4 = w4_0; bb4 = b4_0; }
    else if (a < 8000) { x = x1; C = 256; A = 1600; W = 40; stride = 16.0f; a_local = a - 6400; w2 = w2_1; bb2 = b2_1; w4 = w4_1; bb4 = b4_1; }
    else               { x = x2; C = 512; A = 400;  W = 20; stride = 32.0f; a_local = a - 8000; w2 = w2_2; bb2 = b2_2; w4 = w4_2; bb4 = b4_2; }

    __shared__ float fs[512];
    __shared__ float logits[64];
    __shared__ float kraw[NK];
    __shared__ float dist[4];

    int t = threadIdx.x;
    for (int c = t; c < C; c += 128)
        fs[c] = x[((long)b * C + c) * A + a_local];
    __syncthreads();

    if (t < 64 + NK) {
        const float* wrow; float acc;
        if (t < 64) { wrow = w2 + t * C; acc = bb2[t]; }
        else        { wrow = w4 + (t - 64) * C; acc = bb4[t - 64]; }
#pragma unroll 4
        for (int c = 0; c < C; c += 8) {
            float4 wa = *(const float4*)(wrow + c);
            float4 wb = *(const float4*)(wrow + c + 4);
            float4 fa = *(const float4*)&fs[c];
            float4 fb = *(const float4*)&fs[c + 4];
            acc = fmaf(wa.x, fa.x, acc);
            acc = fmaf(wa.y, fa.y, acc);
            acc = fmaf(wa.z, fa.z, acc);
            acc = fmaf(wa.w, fa.w, acc);
            acc = fmaf(wb.x, fb.x, acc);
            acc = fmaf(wb.y, fb.y, acc);
            acc = fmaf(wb.z, fb.z, acc);
            acc = fmaf(wb.w, fb.w, acc);
        }
        if (t < 64) logits[t] = acc;
        else        kraw[t - 64] = acc;
    }
    __syncthreads();

    if (t < 4) {
        float mx = logits[t * 16];
#pragma unroll
        for (int r = 1; r < 16; ++r) mx = fmaxf(mx, logits[t * 16 + r]);
        float se = 0.0f, sw = 0.0f;
#pragma unroll
        for (int r = 0; r < 16; ++r) {
            float e = expf(logits[t * 16 + r] - mx);
            se += e; sw += e * (float)r;
        }
        dist[t] = sw / se;
    }
    __syncthreads();

    float ax = (float)(a_local % W) + 0.5f;
    float ay = (float)(a_local / W) + 0.5f;

    if (t == 0) {
        float x1c = ax - dist[0], y1c = ay - dist[1];
        float x2c = ax + dist[2], y2c = ay + dist[3];
        float* ob = out + OUT_BOX + ((long)b * MAX_DET + k) * 4;
        ob[0] = (x1c + x2c) * 0.5f * stride;
        ob[1] = (y1c + y2c) * 0.5f * stride;
        ob[2] = (x2c - x1c) * stride;
        ob[3] = (y2c - y1c) * stride;
    }
    if (t < 17) {
        float vx = kraw[t * 3], vy = kraw[t * 3 + 1], vv = kraw[t * 3 + 2];
        float gx = ax - 0.5f, gy = ay - 0.5f;
        float* ok = out + OUT_KPT + (((long)b * MAX_DET + k) * 17 + t) * 3;
        ok[0] = (vx * 2.0f + gx) * stride;
        ok[1] = (vy * 2.0f + gy) * stride;
        ok[2] = 1.0f / (1.0f + expf(-vv));
    }
}

extern "C" void kernel_launch(void* const* d_in, const int* in_sizes, int n_in,
                              void* d_out, int out_size, void* d_ws, size_t ws_size,
                              hipStream_t stream) {
    const float* x0 = (const float*)d_in[0];
    const float* x1 = (const float*)d_in[1];
    const float* x2 = (const float*)d_in[2];
    const float* w2[3] = {(const float*)d_in[3], (const float*)d_in[5], (const float*)d_in[7]};
    const float* b2[3] = {(const float*)d_in[4], (const float*)d_in[6], (const float*)d_in[8]};
    const float* w3[3] = {(const float*)d_in[9], (const float*)d_in[11], (const float*)d_in[13]};
    const float* b3[3] = {(const float*)d_in[10], (const float*)d_in[12], (const float*)d_in[14]};
    const float* w4[3] = {(const float*)d_in[15], (const float*)d_in[17], (const float*)d_in[19]};
    const float* b4[3] = {(const float*)d_in[16], (const float*)d_in[18], (const float*)d_in[20]};

    float* out = (float*)d_out;

    float* ws_maxs = (float*)d_ws;                    // [16][8400]
    int* ws_cls = (int*)(ws_maxs + BS * A_TOT);       // [16][8400]
    int* ws_top = (int*)(ws_cls + BS * A_TOT);        // [16][100]

    // fused scores: 32 (L2) + 112 (L1) + 400 (L0) blocks, 256 anchors each
    scores_fused<<<dim3(544), 256, 0, stream>>>(
        x0, x1, x2, w3[0], w3[1], w3[2], b3[0], b3[1], b3[2], ws_maxs, ws_cls);
    topk_kernel<<<dim3(BS), 1024, 0, stream>>>(ws_maxs, ws_cls, out, ws_top);
    decode_kernel<<<dim3(MAX_DET, BS), 128, 0, stream>>>(
        x0, x1, x2,
        w2[0], b2[0], w2[1], b2[1], w2[2], b2[2],
        w4[0], b4[0], w4[1], b4[1], w4[2], b4[2],
        ws_top, out);
}